// Round 5
// baseline (294.043 us; speedup 1.0000x reference)
//
#include <hip/hip_runtime.h>
#include <math.h>

typedef float f4 __attribute__((ext_vector_type(4)));

// ---------------------------------------------------------------------------
// Kernel 1: E_k = expm(t_k * (M + M0)) via scaling-and-squaring + 12-term
// Taylor. 3x3 only (homogeneous row/col of the 4x4 never contributes since
// x_pad's last coord is 0 and A's last row is 0). One thread per t.
// ---------------------------------------------------------------------------
__global__ void expm_kernel(const float* __restrict__ t,
                            const float* __restrict__ M,
                            const float* __restrict__ M0,
                            float* __restrict__ E_out,
                            int T) {
    int k = blockIdx.x * blockDim.x + threadIdx.x;
    if (k >= T) return;

    float tk = t[k];
    float B[9];
#pragma unroll
    for (int i = 0; i < 9; ++i) B[i] = tk * (M[i] + M0[i]);

    float norm = 0.f;
#pragma unroll
    for (int i = 0; i < 3; ++i) {
        float rs = fabsf(B[i * 3]) + fabsf(B[i * 3 + 1]) + fabsf(B[i * 3 + 2]);
        norm = fmaxf(norm, rs);
    }
    int s = 0;
    while (norm > 0.25f && s < 40) { norm *= 0.5f; ++s; }
    float scale = exp2f((float)(-s));
#pragma unroll
    for (int i = 0; i < 9; ++i) B[i] *= scale;

    float P[9], E[9];
#pragma unroll
    for (int i = 0; i < 9; ++i) { P[i] = (i % 4 == 0) ? 1.f : 0.f; E[i] = P[i]; }
    for (int n = 1; n <= 12; ++n) {
        float inv = 1.0f / (float)n;
        float Q[9];
#pragma unroll
        for (int i = 0; i < 3; ++i)
#pragma unroll
            for (int j = 0; j < 3; ++j)
                Q[i * 3 + j] = (P[i * 3 + 0] * B[0 * 3 + j] +
                                P[i * 3 + 1] * B[1 * 3 + j] +
                                P[i * 3 + 2] * B[2 * 3 + j]) * inv;
#pragma unroll
        for (int i = 0; i < 9; ++i) { P[i] = Q[i]; E[i] += Q[i]; }
    }
    for (int q = 0; q < s; ++q) {
        float Q[9];
#pragma unroll
        for (int i = 0; i < 3; ++i)
#pragma unroll
            for (int j = 0; j < 3; ++j)
                Q[i * 3 + j] = E[i * 3 + 0] * E[0 * 3 + j] +
                               E[i * 3 + 1] * E[1 * 3 + j] +
                               E[i * 3 + 2] * E[2 * 3 + j];
#pragma unroll
        for (int i = 0; i < 9; ++i) E[i] = Q[i];
    }

#pragma unroll
    for (int i = 0; i < 9; ++i) E_out[k * 9 + i] = E[i];
}

// ---------------------------------------------------------------------------
// Kernel 2 (fill-mimicking streamer): no LDS, no barriers, no block churn.
// grid = (32, T) = 2048 blocks == exactly-resident (8 blocks/CU, 32 waves/CU).
// Each block pins one t, hoists E into registers ONCE, then grid-strides over
// groups of 4 rows: 3 float4 loads (48 B = 4 rows, zero redundancy), 36 FMAs,
// 3 nontemporal float4 stores. All 2048 blocks sweep the same x window in
// lockstep -> reads are L2/L3 hits (~6 MB HBM total); writes stream linearly.
// ---------------------------------------------------------------------------
#define BPT 32
#define TPB 256

__global__ __launch_bounds__(TPB) void apply_kernel(const float* __restrict__ x,
                                                    const float* __restrict__ E_all,
                                                    float* __restrict__ out,
                                                    int N) {
    const int t = blockIdx.y;

    float E0, E1, E2, E3, E4, E5, E6, E7, E8;
    {
        const float* Ep = E_all + t * 9;
        E0 = Ep[0]; E1 = Ep[1]; E2 = Ep[2];
        E3 = Ep[3]; E4 = Ep[4]; E5 = Ep[5];
        E6 = Ep[6]; E7 = Ep[7]; E8 = Ep[8];
    }

    const int NG = N >> 2;                       // groups of 4 rows
    const f4* __restrict__ x4 = (const f4*)x;
    f4* out4 = (f4*)out + (size_t)t * (size_t)(N * 3 / 4);
    const int stride = gridDim.x * TPB;          // 8192

#pragma unroll 2
    for (int g = blockIdx.x * TPB + threadIdx.x; g < NG; g += stride) {
        const int b = 3 * g;
        const f4 xa = x4[b + 0];
        const f4 xb = x4[b + 1];
        const f4 xc = x4[b + 2];

        // rows: r0=(xa.xyz) r1=(xa.w,xb.xy) r2=(xb.zw,xc.x) r3=(xc.yzw)
        const float o00 = E0 * xa.x + E1 * xa.y + E2 * xa.z;
        const float o01 = E3 * xa.x + E4 * xa.y + E5 * xa.z;
        const float o02 = E6 * xa.x + E7 * xa.y + E8 * xa.z;

        const float o10 = E0 * xa.w + E1 * xb.x + E2 * xb.y;
        const float o11 = E3 * xa.w + E4 * xb.x + E5 * xb.y;
        const float o12 = E6 * xa.w + E7 * xb.x + E8 * xb.y;

        const float o20 = E0 * xb.z + E1 * xb.w + E2 * xc.x;
        const float o21 = E3 * xb.z + E4 * xb.w + E5 * xc.x;
        const float o22 = E6 * xb.z + E7 * xb.w + E8 * xc.x;

        const float o30 = E0 * xc.y + E1 * xc.z + E2 * xc.w;
        const float o31 = E3 * xc.y + E4 * xc.z + E5 * xc.w;
        const float o32 = E6 * xc.y + E7 * xc.z + E8 * xc.w;

        const f4 oa = {o00, o01, o02, o10};
        const f4 ob = {o11, o12, o20, o21};
        const f4 oc = {o22, o30, o31, o32};

        __builtin_nontemporal_store(oa, out4 + b + 0);
        __builtin_nontemporal_store(ob, out4 + b + 1);
        __builtin_nontemporal_store(oc, out4 + b + 2);
    }

    // tail rows (N % 4) — N=500000 is divisible by 4, but stay general.
    const int rem = N & 3;
    if (rem && blockIdx.x == 0 && threadIdx.x < rem * 3) {
        const int n = (N & ~3) + threadIdx.x / 3;
        const int i = threadIdx.x % 3;
        const float* xr = x + (size_t)n * 3;
        const float* Er = E_all + t * 9 + i * 3;
        out[(size_t)t * N * 3 + (size_t)n * 3 + i] =
            Er[0] * xr[0] + Er[1] * xr[1] + Er[2] * xr[2];
    }
}

extern "C" void kernel_launch(void* const* d_in, const int* in_sizes, int n_in,
                              void* d_out, int out_size, void* d_ws, size_t ws_size,
                              hipStream_t stream) {
    const float* x  = (const float*)d_in[0];   // (N, 3)
    const float* t  = (const float*)d_in[1];   // (T,)
    const float* M  = (const float*)d_in[2];   // (3, 3)
    const float* M0 = (const float*)d_in[3];   // (3, 3)
    // d_in[4] = b (3,) — never contributes: homogeneous coord of x_pad is 0.

    const int N = in_sizes[0] / 3;
    const int T = in_sizes[1];

    float* E_ws = (float*)d_ws;                 // T*9 floats
    float* out  = (float*)d_out;

    expm_kernel<<<(T + 63) / 64, 64, 0, stream>>>(t, M, M0, E_ws, T);

    dim3 grid(BPT, T);
    apply_kernel<<<grid, TPB, 0, stream>>>(x, E_ws, out, N);
}

// Round 6
// 173.210 us; speedup vs baseline: 1.6976x; 1.6976x over previous
//
#include <hip/hip_runtime.h>
#include <math.h>

typedef float f4 __attribute__((ext_vector_type(4)));

// ---------------------------------------------------------------------------
// Kernel 1: E_k = expm(t_k * (M + M0)) via scaling-and-squaring + 12-term
// Taylor. 3x3 only (homogeneous row/col of the 4x4 never contributes since
// x_pad's last coord is 0 and A's last row is 0). One thread per t.
// ---------------------------------------------------------------------------
__global__ void expm_kernel(const float* __restrict__ t,
                            const float* __restrict__ M,
                            const float* __restrict__ M0,
                            float* __restrict__ E_out,
                            int T) {
    int k = blockIdx.x * blockDim.x + threadIdx.x;
    if (k >= T) return;

    float tk = t[k];
    float B[9];
#pragma unroll
    for (int i = 0; i < 9; ++i) B[i] = tk * (M[i] + M0[i]);

    float norm = 0.f;
#pragma unroll
    for (int i = 0; i < 3; ++i) {
        float rs = fabsf(B[i * 3]) + fabsf(B[i * 3 + 1]) + fabsf(B[i * 3 + 2]);
        norm = fmaxf(norm, rs);
    }
    int s = 0;
    while (norm > 0.25f && s < 40) { norm *= 0.5f; ++s; }
    float scale = exp2f((float)(-s));
#pragma unroll
    for (int i = 0; i < 9; ++i) B[i] *= scale;

    float P[9], E[9];
#pragma unroll
    for (int i = 0; i < 9; ++i) { P[i] = (i % 4 == 0) ? 1.f : 0.f; E[i] = P[i]; }
    for (int n = 1; n <= 12; ++n) {
        float inv = 1.0f / (float)n;
        float Q[9];
#pragma unroll
        for (int i = 0; i < 3; ++i)
#pragma unroll
            for (int j = 0; j < 3; ++j)
                Q[i * 3 + j] = (P[i * 3 + 0] * B[0 * 3 + j] +
                                P[i * 3 + 1] * B[1 * 3 + j] +
                                P[i * 3 + 2] * B[2 * 3 + j]) * inv;
#pragma unroll
        for (int i = 0; i < 9; ++i) { P[i] = Q[i]; E[i] += Q[i]; }
    }
    for (int q = 0; q < s; ++q) {
        float Q[9];
#pragma unroll
        for (int i = 0; i < 3; ++i)
#pragma unroll
            for (int j = 0; j < 3; ++j)
                Q[i * 3 + j] = E[i * 3 + 0] * E[0 * 3 + j] +
                               E[i * 3 + 1] * E[1 * 3 + j] +
                               E[i * 3 + 2] * E[2 * 3 + j];
#pragma unroll
        for (int i = 0; i < 9; ++i) E[i] = Q[i];
    }

#pragma unroll
    for (int i = 0; i < 9; ++i) E_out[k * 9 + i] = E[i];
}

// ---------------------------------------------------------------------------
// Kernel 2: persistent + dense stores.
// grid = (BPT, T) = 2048 blocks = exactly resident (8 blocks/CU) -> no churn.
// Each block pins one t (E hoisted to registers once) and strides over
// 1024-row tiles: stage 12 KB of x into LDS with dense f4 loads (L3 hits,
// round 5 proved FETCH ~ 3 MB), then compute and emit DENSE f4 stores —
// consecutive lanes write consecutive 16B, 1024 B contiguous per wave store
// instruction -> full 64B sectors, no write amplification (round 5's strided
// nt stores caused 1.94x WRITE_SIZE; round 1/3's dense stores did not).
// ---------------------------------------------------------------------------
#define BPT 32
#define TPB 256
#define TILE_N 1024

__global__ __launch_bounds__(TPB) void apply_kernel(const float* __restrict__ x,
                                                    const float* __restrict__ E_all,
                                                    float* __restrict__ out,
                                                    int N) {
    __shared__ __align__(16) float xs[TILE_N * 3];

    const int tid = threadIdx.x;
    const int tt  = blockIdx.y;

    float E[9];
#pragma unroll
    for (int i = 0; i < 9; ++i) E[i] = E_all[tt * 9 + i];

    const int ntiles = (N + TILE_N - 1) / TILE_N;

    for (int tile = blockIdx.x; tile < ntiles; tile += BPT) {
        const long n0   = (long)tile * TILE_N;
        const int  rows = min(TILE_N, (int)(N - n0));
        const int  nflt = rows * 3;
        const int  nvec = nflt >> 2;
        const int  rem0 = nvec << 2;

        __syncthreads();   // previous iteration's readers done before restage

        const float* xsrc = x + n0 * 3;   // n0*3 % 4 == 0 -> 16B aligned
        for (int v = tid; v < nvec; v += TPB)
            reinterpret_cast<f4*>(xs)[v] =
                reinterpret_cast<const f4*>(xsrc)[v];
        for (int v = rem0 + tid; v < nflt; v += TPB)
            xs[v] = xsrc[v];
        __syncthreads();

        float* dst = out + ((long)tt * N + n0) * 3;  // 16B aligned
        for (int v = tid; v < nvec; v += TPB) {
            const int e0 = v << 2;
            f4 r;
#pragma unroll
            for (int c = 0; c < 4; ++c) {
                const int e = e0 + c;
                const int n = e / 3;          // magic-mul
                const int i = e - n * 3;
                r[c] = E[i * 3 + 0] * xs[n * 3 + 0] +
                       E[i * 3 + 1] * xs[n * 3 + 1] +
                       E[i * 3 + 2] * xs[n * 3 + 2];
            }
            __builtin_nontemporal_store(r, reinterpret_cast<f4*>(dst) + v);
        }
        for (int v = rem0 + tid; v < nflt; v += TPB) {
            const int n = v / 3;
            const int i = v - n * 3;
            float val = E[i * 3 + 0] * xs[n * 3 + 0] +
                        E[i * 3 + 1] * xs[n * 3 + 1] +
                        E[i * 3 + 2] * xs[n * 3 + 2];
            __builtin_nontemporal_store(val, dst + v);
        }
    }
}

extern "C" void kernel_launch(void* const* d_in, const int* in_sizes, int n_in,
                              void* d_out, int out_size, void* d_ws, size_t ws_size,
                              hipStream_t stream) {
    const float* x  = (const float*)d_in[0];   // (N, 3)
    const float* t  = (const float*)d_in[1];   // (T,)
    const float* M  = (const float*)d_in[2];   // (3, 3)
    const float* M0 = (const float*)d_in[3];   // (3, 3)
    // d_in[4] = b (3,) — never contributes: homogeneous coord of x_pad is 0.

    const int N = in_sizes[0] / 3;
    const int T = in_sizes[1];

    float* E_ws = (float*)d_ws;                 // T*9 floats
    float* out  = (float*)d_out;

    expm_kernel<<<(T + 63) / 64, 64, 0, stream>>>(t, M, M0, E_ws, T);

    dim3 grid(BPT, T);
    apply_kernel<<<grid, TPB, 0, stream>>>(x, E_ws, out, N);
}

// Round 7
// 104.253 us; speedup vs baseline: 2.8205x; 1.6614x over previous
//
#include <hip/hip_runtime.h>
#include <math.h>

typedef float f4 __attribute__((ext_vector_type(4)));

// ---------------------------------------------------------------------------
// Kernel 1: E_k = expm(t_k * (M + M0)) via scaling-and-squaring + 12-term
// Taylor. 3x3 only (homogeneous row/col of the 4x4 never contributes since
// x_pad's last coord is 0 and A's last row is 0). One thread per t.
// ---------------------------------------------------------------------------
__global__ void expm_kernel(const float* __restrict__ t,
                            const float* __restrict__ M,
                            const float* __restrict__ M0,
                            float* __restrict__ E_out,
                            int T) {
    int k = blockIdx.x * blockDim.x + threadIdx.x;
    if (k >= T) return;

    float tk = t[k];
    float B[9];
#pragma unroll
    for (int i = 0; i < 9; ++i) B[i] = tk * (M[i] + M0[i]);

    float norm = 0.f;
#pragma unroll
    for (int i = 0; i < 3; ++i) {
        float rs = fabsf(B[i * 3]) + fabsf(B[i * 3 + 1]) + fabsf(B[i * 3 + 2]);
        norm = fmaxf(norm, rs);
    }
    int s = 0;
    while (norm > 0.25f && s < 40) { norm *= 0.5f; ++s; }
    float scale = exp2f((float)(-s));
#pragma unroll
    for (int i = 0; i < 9; ++i) B[i] *= scale;

    float P[9], E[9];
#pragma unroll
    for (int i = 0; i < 9; ++i) { P[i] = (i % 4 == 0) ? 1.f : 0.f; E[i] = P[i]; }
    for (int n = 1; n <= 12; ++n) {
        float inv = 1.0f / (float)n;
        float Q[9];
#pragma unroll
        for (int i = 0; i < 3; ++i)
#pragma unroll
            for (int j = 0; j < 3; ++j)
                Q[i * 3 + j] = (P[i * 3 + 0] * B[0 * 3 + j] +
                                P[i * 3 + 1] * B[1 * 3 + j] +
                                P[i * 3 + 2] * B[2 * 3 + j]) * inv;
#pragma unroll
        for (int i = 0; i < 9; ++i) { P[i] = Q[i]; E[i] += Q[i]; }
    }
    for (int q = 0; q < s; ++q) {
        float Q[9];
#pragma unroll
        for (int i = 0; i < 3; ++i)
#pragma unroll
            for (int j = 0; j < 3; ++j)
                Q[i * 3 + j] = E[i * 3 + 0] * E[0 * 3 + j] +
                               E[i * 3 + 1] * E[1 * 3 + j] +
                               E[i * 3 + 2] * E[2 * 3 + j];
#pragma unroll
        for (int i = 0; i < 9; ++i) E[i] = Q[i];
    }

#pragma unroll
    for (int i = 0; i < 9; ++i) E_out[k * 9 + i] = E[i];
}

// ---------------------------------------------------------------------------
// Kernel 2: single-rolling-window streamer (fill-pattern mimic).
// 512 blocks x 256 thr = 131072 threads. OUTER loop over t is uniform across
// the whole grid; inner pass covers one 6 MB slab with threads lane-dense:
// thread g handles rows 4g..4g+3 (3 f4 loads, 36 FMA, 3 f4 stores). So at any
// instant the ENTIRE GPU writes one contiguous ~6 MB window sweeping slab by
// slab — the same pattern as fillBufferAligned (measured 7 TB/s), instead of
// 2048 independent 12-48 KB write fronts (rounds 1-6, all ~2.3-2.6 TB/s).
// PLAIN stores (not nt): each wave's 3 strided-16B store instrs jointly cover
// contiguous 3072 B; L2 write-back merges them into full lines (round 5
// proved nt bypasses this merge -> 1.94x write amplification).
// ---------------------------------------------------------------------------
#define NBLK 512
#define TPB 256

__global__ __launch_bounds__(TPB) void apply_kernel(const float* __restrict__ x,
                                                    const float* __restrict__ E_all,
                                                    float* __restrict__ out,
                                                    int N, int T) {
    const int gid      = blockIdx.x * TPB + threadIdx.x;
    const int nthreads = gridDim.x * TPB;

    if ((N & 3) == 0) {
        const int NG = N >> 2;                         // 4-row groups per slab
        const f4* __restrict__ x4 = (const f4*)x;
        const size_t slab4 = (size_t)(N >> 2) * 3;     // f4 per slab

        for (int t = 0; t < T; ++t) {
            const float* Ep = E_all + t * 9;
            const float E0 = Ep[0], E1 = Ep[1], E2 = Ep[2];
            const float E3 = Ep[3], E4 = Ep[4], E5 = Ep[5];
            const float E6 = Ep[6], E7 = Ep[7], E8 = Ep[8];
            f4* out4 = (f4*)out + (size_t)t * slab4;

            for (int g = gid; g < NG; g += nthreads) {
                const int b = 3 * g;
                const f4 xa = x4[b + 0];
                const f4 xb = x4[b + 1];
                const f4 xc = x4[b + 2];

                // rows: r0=(xa.xyz) r1=(xa.w,xb.xy) r2=(xb.zw,xc.x) r3=(xc.yzw)
                f4 oa, ob, oc;
                oa.x = E0 * xa.x + E1 * xa.y + E2 * xa.z;
                oa.y = E3 * xa.x + E4 * xa.y + E5 * xa.z;
                oa.z = E6 * xa.x + E7 * xa.y + E8 * xa.z;

                oa.w = E0 * xa.w + E1 * xb.x + E2 * xb.y;
                ob.x = E3 * xa.w + E4 * xb.x + E5 * xb.y;
                ob.y = E6 * xa.w + E7 * xb.x + E8 * xb.y;

                ob.z = E0 * xb.z + E1 * xb.w + E2 * xc.x;
                ob.w = E3 * xb.z + E4 * xb.w + E5 * xc.x;
                oc.x = E6 * xb.z + E7 * xb.w + E8 * xc.x;

                oc.y = E0 * xc.y + E1 * xc.z + E2 * xc.w;
                oc.z = E3 * xc.y + E4 * xc.z + E5 * xc.w;
                oc.w = E6 * xc.y + E7 * xc.z + E8 * xc.w;

                out4[b + 0] = oa;
                out4[b + 1] = ob;
                out4[b + 2] = oc;
            }
        }
    } else {
        // generic scalar fallback (not hit for N % 4 == 0)
        const size_t total = (size_t)T * (size_t)N * 3;
        for (size_t e = gid; e < total; e += (size_t)nthreads) {
            const size_t slab = (size_t)N * 3;
            const int    t    = (int)(e / slab);
            const size_t r    = e - (size_t)t * slab;
            const int    n    = (int)(r / 3);
            const int    i    = (int)(r - (size_t)n * 3);
            const float* Ep = E_all + t * 9 + i * 3;
            const float* xr = x + (size_t)n * 3;
            out[e] = Ep[0] * xr[0] + Ep[1] * xr[1] + Ep[2] * xr[2];
        }
    }
}

extern "C" void kernel_launch(void* const* d_in, const int* in_sizes, int n_in,
                              void* d_out, int out_size, void* d_ws, size_t ws_size,
                              hipStream_t stream) {
    const float* x  = (const float*)d_in[0];   // (N, 3)
    const float* t  = (const float*)d_in[1];   // (T,)
    const float* M  = (const float*)d_in[2];   // (3, 3)
    const float* M0 = (const float*)d_in[3];   // (3, 3)
    // d_in[4] = b (3,) — never contributes: homogeneous coord of x_pad is 0.

    const int N = in_sizes[0] / 3;
    const int T = in_sizes[1];

    float* E_ws = (float*)d_ws;                 // T*9 floats
    float* out  = (float*)d_out;

    expm_kernel<<<(T + 63) / 64, 64, 0, stream>>>(t, M, M0, E_ws, T);

    apply_kernel<<<NBLK, TPB, 0, stream>>>(x, E_ws, out, N, T);
}